// Round 1
// baseline (297.524 us; speedup 1.0000x reference)
//
#include <hip/hip_runtime.h>
#include <hip/hip_bf16.h>

typedef __bf16 bf16_t;
typedef __attribute__((ext_vector_type(8))) __bf16 bf16x8;
typedef __attribute__((ext_vector_type(4))) __bf16 bf16x4;
typedef __attribute__((ext_vector_type(4))) float floatx4;

#define NB 8192   // rows of x (B)
#define NC 8192   // rows of y (C)
#define ND 256    // feature dim D
#define BM 128
#define BN 128
#define BK 32

typedef __attribute__((address_space(3))) void lds_void_t;
typedef __attribute__((address_space(1))) void gl_void_t;

// ---------------------------------------------------------------------------
// prep: fp32 -> bf16 copies of x and y (for global_load_lds staging in the
// GEMM), plus row squared-norms x2/y2 in fp32. One wave per row (256 floats =
// 64 lanes x float4).
// ---------------------------------------------------------------------------
__global__ __launch_bounds__(256) void prep_kernel(
    const float* __restrict__ x, const float* __restrict__ y,
    bf16_t* __restrict__ xb, bf16_t* __restrict__ yb,
    float* __restrict__ x2, float* __restrict__ y2)
{
    int t    = threadIdx.x;
    int wave = t >> 6;
    int lane = t & 63;
    int row  = blockIdx.x * 4 + wave;   // 0..16383 (x rows then y rows)

    const float* src;
    bf16_t* dst;
    float* nrm;
    int r;
    if (row < NB) { src = x; dst = xb; nrm = x2; r = row; }
    else          { src = y; dst = yb; nrm = y2; r = row - NB; }

    float4 v = ((const float4*)(src + (size_t)r * ND))[lane];
    float ss = v.x * v.x + v.y * v.y + v.z * v.z + v.w * v.w;

    bf16x4 o;
    o.x = (__bf16)v.x; o.y = (__bf16)v.y; o.z = (__bf16)v.z; o.w = (__bf16)v.w;
    ((bf16x4*)(dst + (size_t)r * ND))[lane] = o;

    #pragma unroll
    for (int off = 32; off >= 1; off >>= 1)
        ss += __shfl_xor(ss, off, 64);
    if (lane == 0) nrm[r] = ss;
}

// ---------------------------------------------------------------------------
// RBF GEMM: out[b,c] = exp(-gamma * max(x2[b] + y2[c] - 2*dot(x_b, y_c), 0))
// m97 structure: 128x128 tile, BK=32, 256 threads (4 waves, 2x2), each wave a
// 64x64 subtile = 4x4 MFMA 16x16x32 bf16. global_load_lds width=16 staging.
// ---------------------------------------------------------------------------
__global__ __launch_bounds__(256) void rbf_gemm_kernel(
    const bf16_t* __restrict__ xb, const bf16_t* __restrict__ yb,
    const float* __restrict__ x2, const float* __restrict__ y2,
    const float* __restrict__ gamma_p, float* __restrict__ out)
{
    __shared__ bf16_t lA[BM * BK];   // 8 KB, row-major 128x32 (row = 64 B)
    __shared__ bf16_t lB[BN * BK];   // 8 KB

    const int t    = threadIdx.x;
    const int lane = t & 63;
    const int wave = t >> 6;
    const int wm   = wave >> 1;      // 0..1 : wave row in 2x2 wave grid
    const int wn   = wave & 1;       // 0..1
    const int quad = lane >> 4;      // 0..3
    const int l15  = lane & 15;

    const int bm = blockIdx.x * BM;  // x-row base
    const int bn = blockIdx.y * BN;  // y-row (output col) base

    const float gamma = *gamma_p;

    floatx4 acc[4][4];
    #pragma unroll
    for (int i = 0; i < 4; ++i)
        #pragma unroll
        for (int j = 0; j < 4; ++j)
            acc[i][j] = (floatx4){0.f, 0.f, 0.f, 0.f};

    // Staging geometry: 8 KB tile = 512 chunks of 16 B; thread t, call c owns
    // chunk li = c*256 + t -> tile row = li>>2, k-byte = (li&3)*16.
    // Row stride in global bf16 array: ND*2 = 512 B; k-tile step: BK*2 = 64 B.
    const char* gA = (const char*)xb + (size_t)bm * (ND * 2);
    const char* gB = (const char*)yb + (size_t)bn * (ND * 2);

    for (int kt = 0; kt < ND / BK; ++kt) {
        __syncthreads();   // previous iteration's reads done before overwrite
        #pragma unroll
        for (int c = 0; c < 2; ++c) {
            const int li  = c * 256 + t;
            const int row = li >> 2;
            const int kb  = (li & 3) * 16;
            const size_t goff = (size_t)row * (ND * 2) + kt * (BK * 2) + kb;
            __builtin_amdgcn_global_load_lds(
                (gl_void_t*)(gA + goff),
                (lds_void_t*)((char*)lA + (size_t)li * 16), 16, 0, 0);
            __builtin_amdgcn_global_load_lds(
                (gl_void_t*)(gB + goff),
                (lds_void_t*)((char*)lB + (size_t)li * 16), 16, 0, 0);
        }
        __syncthreads();   // compiler emits s_waitcnt vmcnt(0) before barrier

        bf16x8 af[4], bfr[4];
        #pragma unroll
        for (int i = 0; i < 4; ++i) {
            const int ar = wm * 64 + i * 16 + l15;
            af[i]  = *(const bf16x8*)((const char*)lA + ar * (BK * 2) + quad * 16);
            const int br = wn * 64 + i * 16 + l15;
            bfr[i] = *(const bf16x8*)((const char*)lB + br * (BK * 2) + quad * 16);
        }
        #pragma unroll
        for (int i = 0; i < 4; ++i)
            #pragma unroll
            for (int j = 0; j < 4; ++j)
                acc[i][j] = __builtin_amdgcn_mfma_f32_16x16x32_bf16(
                    af[i], bfr[j], acc[i][j], 0, 0, 0);
    }

    // Epilogue. C/D layout: col = lane&15, row = quad*4 + reg  [m89/m91].
    #pragma unroll
    for (int i = 0; i < 4; ++i) {
        const int grow0 = bm + wm * 64 + i * 16 + quad * 4;
        float xn[4];
        #pragma unroll
        for (int r = 0; r < 4; ++r) xn[r] = x2[grow0 + r];
        #pragma unroll
        for (int j = 0; j < 4; ++j) {
            const int gcol = bn + wn * 64 + j * 16 + l15;
            const float yn = y2[gcol];
            #pragma unroll
            for (int r = 0; r < 4; ++r) {
                float sq = xn[r] + yn - 2.0f * acc[i][j][r];
                sq = fmaxf(sq, 0.0f);
                out[(size_t)(grow0 + r) * NC + gcol] = __expf(-gamma * sq);
            }
        }
    }
}

extern "C" void kernel_launch(void* const* d_in, const int* in_sizes, int n_in,
                              void* d_out, int out_size, void* d_ws, size_t ws_size,
                              hipStream_t stream) {
    const float* x = (const float*)d_in[0];
    const float* y = (const float*)d_in[1];
    const float* gamma = (const float*)d_in[2];
    float* out = (float*)d_out;

    // Workspace layout: xb (4 MB) | yb (4 MB) | x2 (32 KB) | y2 (32 KB)
    bf16_t* xb = (bf16_t*)d_ws;
    bf16_t* yb = xb + (size_t)NB * ND;
    float*  x2 = (float*)(yb + (size_t)NC * ND);
    float*  y2 = x2 + NB;

    prep_kernel<<<dim3((NB + NC) / 4), dim3(256), 0, stream>>>(x, y, xb, yb, x2, y2);
    rbf_gemm_kernel<<<dim3(NB / BM, NC / BN), dim3(256), 0, stream>>>(
        xb, yb, x2, y2, gamma, out);
}